// Round 1
// baseline (306.384 us; speedup 1.0000x reference)
//
#include <hip/hip_runtime.h>

// VectorQuantizer: inputs [8,4096,64] f32, weight [8192,64] f32.
// Outputs concat: quantized_st [2097152] f32, loss [1] f32, indices [32768] f32.
//
// R5: VALU-lean argmin. packedW holds bf16 split of (-2*w); wsq+BIAS is folded
// into the MFMA accumulator init, so acc[r] == biased distance c = wsq+8-2*dot.
// Top-2 tracking runs in unsigned-key space: key = (bits(c) & ~0x7F) | tile_id
// (positive floats order as uints; 7-bit in-chunk tile id embedded in the low
// mantissa). 4 VALU ops/element, no cndmask. Packing error <= 128 ULP (<1.3e-4,
// one-sided), bf16-split error ~5e-5: MARGIN=4e-4 routes all ambiguous rows to
// the np-exact recheck. 2-phase double-buffered LDS staging (loads issued before
// compute, 1 barrier/group). KSPLIT=4 -> 1024 blocks, 4/CU. Kernels fused: 5
// dispatches total, no memsets.

typedef short bf16x8 __attribute__((ext_vector_type(8)));
typedef float f32x4  __attribute__((ext_vector_type(4)));

#define N_ROWS 32768
#define DIM 64
#define K_CODES 8192
#define KSPLIT 4
#define KCHUNK 2048
#define OUT_Q 0
#define OUT_LOSS 2097152
#define OUT_IDX 2097153
#define MARGIN 4e-4f
#define KEYMASK 0xFFFFFF80u

// ---- helpers ----
__device__ __forceinline__ unsigned short bf16_rne(float f) {
    unsigned u = __float_as_uint(f);
    u += 0x7fffu + ((u >> 16) & 1u);
    return (unsigned short)(u >> 16);
}
__device__ __forceinline__ float bf16_to_f(unsigned short h) {
    return __uint_as_float(((unsigned)h) << 16);
}

// numpy pairwise_sum over 64 squared elements (exact np emulation)
__device__ __forceinline__ float np_pairwise_sq64(const float* v) {
    float r[8];
#pragma unroll
    for (int j = 0; j < 8; j++) r[j] = __fmul_rn(v[j], v[j]);
#pragma unroll
    for (int i = 8; i < 64; i += 8) {
#pragma unroll
        for (int j = 0; j < 8; j++)
            r[j] = __fadd_rn(r[j], __fmul_rn(v[i + j], v[i + j]));
    }
    return __fadd_rn(__fadd_rn(__fadd_rn(r[0], r[1]), __fadd_rn(r[2], r[3])),
                     __fadd_rn(__fadd_rn(r[4], r[5]), __fadd_rn(r[6], r[7])));
}

// ---------------- kernel 0: prep (wsq + wsqb + packedW + zero-init) ----------
// grid 128 x 256. Per block: 64 codes of wsq (tid<64), 4 packed tiles (per wave).
// packedW layout: [tile(512)][frag(4)][lane(64)] x 16B,
// frag: 0=hi_k0 1=hi_k32 2=lo_k0 3=lo_k32, values are bf16 split of (-2*w).
// B-frag (16x16x32): lane holds B[k=(lane>>4)*8+j][n=lane&15], bf16 x8.
__global__ __launch_bounds__(256) void vq_prep(const float* __restrict__ weight,
                                               float* __restrict__ wsq,
                                               float* __restrict__ wsqb,
                                               int4* __restrict__ packedW,
                                               int* __restrict__ rcount,
                                               float* __restrict__ loss_out) {
    int tid = threadIdx.x;
    if (blockIdx.x == 0 && tid == 0) { *rcount = 0; *loss_out = 0.f; }

    if (tid < 64) {
        int k = blockIdx.x * 64 + tid;
        float w[64];
        const float4* wp = (const float4*)(weight + (size_t)k * DIM);
#pragma unroll
        for (int i = 0; i < 16; i++) {
            float4 t = wp[i];
            w[4 * i] = t.x; w[4 * i + 1] = t.y; w[4 * i + 2] = t.z; w[4 * i + 3] = t.w;
        }
        float s = np_pairwise_sq64(w);
        wsq[k] = s;
        wsqb[k] = s + 8.0f;   // BIAS folded for the MFMA accumulator init
    }

    int wave = tid >> 6;
    int lane = tid & 63;
    int tile = blockIdx.x * 4 + wave;     // 0..511
    int code = tile * 16 + (lane & 15);
    int kq = (lane >> 4) * 8;
    const float* wr = weight + (size_t)code * DIM;

    union { bf16x8 v; int4 q; } hi0, hi1, lo0, lo1;
#pragma unroll
    for (int j = 0; j < 8; j++) {
        float a = -2.0f * wr[kq + j];
        unsigned short ha = bf16_rne(a);
        hi0.v[j] = (short)ha;
        lo0.v[j] = (short)bf16_rne(a - bf16_to_f(ha));
        float b = -2.0f * wr[32 + kq + j];
        unsigned short hb = bf16_rne(b);
        hi1.v[j] = (short)hb;
        lo1.v[j] = (short)bf16_rne(b - bf16_to_f(hb));
    }
    size_t base = (size_t)tile * 4 * 64;
    packedW[base + 0 * 64 + lane] = hi0.q;
    packedW[base + 1 * 64 + lane] = hi1.q;
    packedW[base + 2 * 64 + lane] = lo0.q;
    packedW[base + 3 * 64 + lane] = lo1.q;
}

// ---------------- kernel 1: MFMA argmin top-2 over a 2048-code chunk ----------
// grid (256, KSPLIT) x 256. Block: 128 rows; wave: 32 rows (2 row-tiles).
__global__ __launch_bounds__(256) void vq_argmin_mfma(const float* __restrict__ inp,
                                                      const int4* __restrict__ packedW,
                                                      const float* __restrict__ wsqb,
                                                      unsigned long long* __restrict__ bestk,
                                                      unsigned* __restrict__ secd) {
    __shared__ int4 sB[2048];   // 32 KB: two 16 KB buffers (4 code-tiles each)
    int wave = threadIdx.x >> 6;
    int lane = threadIdx.x & 63;
    int rbase = blockIdx.x * 128 + wave * 32;
    int kbase = blockIdx.y * KCHUNK;

    // A fragments from raw fp32 rows: lane holds A[m=lane&15][k=(lane>>4)*8+j]
    int kq = (lane >> 4) * 8;
    bf16x8 ah[2][2], al[2][2];   // [row-tile][k-chunk]
#pragma unroll
    for (int rt = 0; rt < 2; rt++) {
        const float* xp = inp + (size_t)(rbase + rt * 16 + (lane & 15)) * DIM;
#pragma unroll
        for (int kc = 0; kc < 2; kc++) {
            const float* xq = xp + kc * 32 + kq;
#pragma unroll
            for (int j = 0; j < 8; j++) {
                float a = xq[j];
                unsigned short h = bf16_rne(a);
                ah[rt][kc][j] = (short)h;
                al[rt][kc][j] = (short)bf16_rne(a - bf16_to_f(h));
            }
        }
    }

    unsigned best[8], sec[8];
#pragma unroll
    for (int s = 0; s < 8; s++) { best[s] = 0xFFFFFFFFu; sec[s] = 0xFFFFFFFFu; }

    // stage one 16 KB group (4 tiles, wave w stages tile w) into buffer `buf`
#define STAGE(buf, g) do {                                                        \
        const char* _src = (const char*)packedW +                                 \
            ((size_t)(kbase >> 4) + (size_t)(g) * 4 + wave) * 4096;               \
        char* _dst = (char*)sB + (buf) * 16384 + wave * 4096;                     \
        _Pragma("unroll")                                                         \
        for (int _i = 0; _i < 4; _i++)                                            \
            __builtin_amdgcn_global_load_lds(                                     \
                (const __attribute__((address_space(1))) unsigned int*)(_src + _i * 1024 + lane * 16), \
                (__attribute__((address_space(3))) unsigned int*)(_dst + _i * 1024), \
                16, 0, 0);                                                        \
    } while (0)

    STAGE(0, 0);
    __syncthreads();   // drains vmcnt(0): buf0 ready

    for (int g = 0; g < 32; g++) {
        int buf = g & 1;
        if (g + 1 < 32) STAGE(buf ^ 1, g + 1);   // issue next-group loads FIRST
        int cb = kbase + g * 64 + (lane & 15);
#pragma unroll
        for (int t = 0; t < 4; t++) {
            const int4* bp = sB + buf * 1024 + t * 256;
            union { int4 q; bf16x8 v; } bh0, bh1, bl0, bl1;
            bh0.q = bp[0 * 64 + lane];
            bh1.q = bp[1 * 64 + lane];
            bl0.q = bp[2 * 64 + lane];
            bl1.q = bp[3 * 64 + lane];
            float wq = wsqb[cb + t * 16];
            unsigned tid7 = (unsigned)(g * 4 + t);   // 0..127 tile id in chunk
#pragma unroll
            for (int rt = 0; rt < 2; rt++) {
                f32x4 acc = {wq, wq, wq, wq};   // c = wsq + 8 - 2*dot, directly
                acc = __builtin_amdgcn_mfma_f32_16x16x32_bf16(ah[rt][0], bh0.v, acc, 0, 0, 0);
                acc = __builtin_amdgcn_mfma_f32_16x16x32_bf16(ah[rt][1], bh1.v, acc, 0, 0, 0);
                acc = __builtin_amdgcn_mfma_f32_16x16x32_bf16(al[rt][0], bh0.v, acc, 0, 0, 0);
                acc = __builtin_amdgcn_mfma_f32_16x16x32_bf16(al[rt][1], bh1.v, acc, 0, 0, 0);
                acc = __builtin_amdgcn_mfma_f32_16x16x32_bf16(ah[rt][0], bl0.v, acc, 0, 0, 0);
                acc = __builtin_amdgcn_mfma_f32_16x16x32_bf16(ah[rt][1], bl1.v, acc, 0, 0, 0);
#pragma unroll
                for (int r = 0; r < 4; r++) {
                    // 4 VALU ops: v_and_or_b32, v_max_u32, v_min_u32, v_min_u32
                    unsigned key = (__float_as_uint(acc[r]) & KEYMASK) | tid7;
                    int s = rt * 4 + r;
                    unsigned mx = best[s] > key ? best[s] : key;
                    sec[s] = sec[s] < mx ? sec[s] : mx;
                    best[s] = best[s] < key ? best[s] : key;
                }
            }
        }
        __syncthreads();   // one barrier per group; also drains next-group loads
    }
#undef STAGE

    // reduce across the 16 code-columns (lanes sharing lane>>4 group)
    unsigned col[8];
#pragma unroll
    for (int s = 0; s < 8; s++) col[s] = lane & 15;
#pragma unroll
    for (int m = 1; m < 16; m <<= 1) {
#pragma unroll
        for (int s = 0; s < 8; s++) {
            unsigned ok = (unsigned)__shfl_xor((int)best[s], m, 64);
            unsigned os = (unsigned)__shfl_xor((int)sec[s], m, 64);
            unsigned oc = (unsigned)__shfl_xor((int)col[s], m, 64);
            unsigned mx = best[s] > ok ? best[s] : ok;
            unsigned mn2 = sec[s] < os ? sec[s] : os;
            sec[s] = mn2 < mx ? mn2 : mx;
            bool take = ok < best[s];
            best[s] = take ? ok : best[s];
            col[s] = take ? oc : col[s];
        }
    }
    if ((lane & 15) == 0) {
        int g4 = lane >> 4;
#pragma unroll
        for (int rt = 0; rt < 2; rt++)
#pragma unroll
            for (int r = 0; r < 4; r++) {
                int row = rbase + rt * 16 + g4 * 4 + r;
                int s = rt * 4 + r;
                int code = kbase + (int)(best[s] & 127u) * 16 + (int)col[s];
                bestk[(size_t)blockIdx.y * N_ROWS + row] =
                    ((unsigned long long)best[s] << 32) | (unsigned)code;
                secd[(size_t)blockIdx.y * N_ROWS + row] = sec[s];
            }
    }
}

// ---------------- kernel 2: merge chunks, flag near-ties ----------------
__global__ __launch_bounds__(256) void vq_merge(const unsigned long long* __restrict__ bestk,
                                                const unsigned* __restrict__ secd,
                                                int* __restrict__ final_idx,
                                                int* __restrict__ recheck_rows,
                                                int* __restrict__ recheck_count) {
    int row = blockIdx.x * 256 + threadIdx.x;

    unsigned long long ks[KSPLIT];
    unsigned ss[KSPLIT];
#pragma unroll
    for (int c = 0; c < KSPLIT; c++) {
        ks[c] = bestk[(size_t)c * N_ROWS + row];
        ss[c] = secd[(size_t)c * N_ROWS + row];
    }

    unsigned long long k1 = ks[0];
#pragma unroll
    for (int c = 1; c < KSPLIT; c++) k1 = (ks[c] < k1) ? ks[c] : k1;

    unsigned d2 = 0xFFFFFFFFu;
#pragma unroll
    for (int c = 0; c < KSPLIT; c++) {
        if (ks[c] != k1) {
            unsigned b = (unsigned)(ks[c] >> 32);
            d2 = b < d2 ? b : d2;
        }
        d2 = ss[c] < d2 ? ss[c] : d2;
    }

    final_idx[row] = (int)(k1 & 0xffffffffull);
    float f1 = __uint_as_float(((unsigned)(k1 >> 32)) & KEYMASK);
    float f2 = __uint_as_float(d2 & KEYMASK);
    if (f2 - f1 < MARGIN) {
        int slot = atomicAdd(recheck_count, 1);
        recheck_rows[slot] = row;
    }
}

// ---------------- kernel 3: np-exact rescan of flagged rows ----------------
__global__ __launch_bounds__(256) void vq_recheck_np(const float* __restrict__ inp,
                                                     const float* __restrict__ weight,
                                                     const float* __restrict__ wsq,
                                                     const int* __restrict__ recheck_rows,
                                                     const int* __restrict__ recheck_count,
                                                     int* __restrict__ final_idx) {
    __shared__ float xs[DIM];
    __shared__ float x2s;
    __shared__ float rd[256];
    __shared__ int   ri[256];
    int tid = threadIdx.x;
    int cnt = *recheck_count;
    if (cnt > N_ROWS) cnt = N_ROWS;

    for (int li = blockIdx.x; li < cnt; li += gridDim.x) {
        int row = recheck_rows[li];
        if (tid < DIM) xs[tid] = inp[(size_t)row * DIM + tid];
        __syncthreads();
        if (tid == 0) x2s = np_pairwise_sq64(xs);
        __syncthreads();
        float x2 = x2s;

        float bd = 3.402823466e+38f;
        int bi = 0x7fffffff;
        for (int code = tid; code < K_CODES; code += 256) {
            const float* wp = weight + (size_t)code * DIM;
            float s = 0.f;
#pragma unroll
            for (int i = 0; i < DIM; i++) s = __builtin_fmaf(xs[i], wp[i], s);
            float t1 = __fadd_rn(x2, wsq[code]);
            float d  = __fsub_rn(t1, __fmul_rn(2.0f, s));
            if (d < bd) { bd = d; bi = code; }
        }
        rd[tid] = bd; ri[tid] = bi;
        __syncthreads();
        for (int s = 128; s > 0; s >>= 1) {
            if (tid < s) {
                if (rd[tid + s] < rd[tid] ||
                    (rd[tid + s] == rd[tid] && ri[tid + s] < ri[tid])) {
                    rd[tid] = rd[tid + s]; ri[tid] = ri[tid + s];
                }
            }
            __syncthreads();
        }
        if (tid == 0) final_idx[row] = ri[0];
        __syncthreads();
    }
}

// ---------------- kernel 4: gather + STE + loss + index write ----------------
__global__ __launch_bounds__(256) void vq_final(const float* __restrict__ inp,
                                                const float* __restrict__ weight,
                                                const int* __restrict__ final_idx,
                                                float* __restrict__ out) {
    int gid = blockIdx.x * 256 + threadIdx.x;
    int row = gid >> 4;
    int sub = gid & 15;

    int idx = final_idx[row];

    float4 x = ((const float4*)inp)[gid];
    float4 w = ((const float4*)weight)[idx * 16 + sub];

    float4 q;
    q.x = x.x + (w.x - x.x);
    q.y = x.y + (w.y - x.y);
    q.z = x.z + (w.z - x.z);
    q.w = x.w + (w.w - x.w);
    ((float4*)(out + OUT_Q))[gid] = q;

    if (sub == 0) out[OUT_IDX + row] = (float)idx;

    float dx = w.x - x.x, dy = w.y - x.y, dz = w.z - x.z, dw = w.w - x.w;
    float lp = dx * dx + dy * dy + dz * dz + dw * dw;

#pragma unroll
    for (int o = 32; o > 0; o >>= 1) lp += __shfl_down(lp, o, 64);

    __shared__ float red[4];
    int wid = threadIdx.x >> 6;
    int lane = threadIdx.x & 63;
    if (lane == 0) red[wid] = lp;
    __syncthreads();
    if (threadIdx.x == 0) {
        float bs = red[0] + red[1] + red[2] + red[3];
        atomicAdd(out + OUT_LOSS, bs * (0.25f / 2097152.f));
    }
}

extern "C" void kernel_launch(void* const* d_in, const int* in_sizes, int n_in,
                              void* d_out, int out_size, void* d_ws, size_t ws_size,
                              hipStream_t stream) {
    const float* inp = (const float*)d_in[0];
    const float* weight = (const float*)d_in[1];
    float* out = (float*)d_out;

    char* ws = (char*)d_ws;
    unsigned long long* bestk = (unsigned long long*)ws;               // 1 MB
    unsigned* secd  = (unsigned*)(ws + (size_t)KSPLIT * N_ROWS * 8);   // 512 KB
    char* p         = ws + (size_t)KSPLIT * N_ROWS * 12;
    int* final_idx  = (int*)p;                                         // 128 KB
    int* rrows      = (int*)(p + (size_t)N_ROWS * 4);                  // 128 KB
    int* rcount     = (int*)(p + (size_t)N_ROWS * 8);                  // 256 B
    float* wsq      = (float*)(p + (size_t)N_ROWS * 8 + 256);          // 32 KB
    float* wsqb     = (float*)(p + (size_t)N_ROWS * 8 + 256 + 32768);  // 32 KB
    int4* packedW   = (int4*)(p + (size_t)N_ROWS * 8 + 256 + 65536);   // 2 MB

    vq_prep<<<128, 256, 0, stream>>>(weight, wsq, wsqb, packedW, rcount, out + OUT_LOSS);
    vq_argmin_mfma<<<dim3(N_ROWS / 128, KSPLIT), 256, 0, stream>>>(inp, packedW, wsqb, bestk, secd);
    vq_merge<<<N_ROWS / 256, 256, 0, stream>>>(bestk, secd, final_idx, rrows, rcount);
    vq_recheck_np<<<128, 256, 0, stream>>>(inp, weight, wsq, rrows, rcount, final_idx);
    vq_final<<<(N_ROWS * DIM / 4) / 256, 256, 0, stream>>>(inp, weight, final_idx, out);
}

// Round 2
// 246.272 us; speedup vs baseline: 1.2441x; 1.2441x over previous
//
#include <hip/hip_runtime.h>

// VectorQuantizer: inputs [8,4096,64] f32, weight [8192,64] f32.
// Outputs concat: quantized_st [2097152] f32, loss [1] f32, indices [32768] f32.
//
// R6: parallel cnt-proportional recheck. R5's argmin (VALU-lean key-space top-2,
// double-buffered staging, KSPLIT=4) kept unchanged. Recheck restructured:
// grid (256 row-slots, 8 code-slices); each block scans 1024 codes np-exactly
// for one flagged row; slices combine via atomicMin on u64 ordered key
// (ord(dist)<<32 | idx) == exact np argmin tie-break (smallest dist, then
// smallest index). Slot keys initialized by vq_merge at flag time. A tiny
// scatter dispatch writes winners to final_idx before vq_final.

typedef short bf16x8 __attribute__((ext_vector_type(8)));
typedef float f32x4  __attribute__((ext_vector_type(4)));

#define N_ROWS 32768
#define DIM 64
#define K_CODES 8192
#define KSPLIT 4
#define KCHUNK 2048
#define OUT_Q 0
#define OUT_LOSS 2097152
#define OUT_IDX 2097153
#define MARGIN 4e-4f
#define KEYMASK 0xFFFFFF80u

// ---- helpers ----
__device__ __forceinline__ unsigned f2u_ord(float f) {
    unsigned u = __float_as_uint(f);
    return (u & 0x80000000u) ? ~u : (u | 0x80000000u);
}
__device__ __forceinline__ unsigned short bf16_rne(float f) {
    unsigned u = __float_as_uint(f);
    u += 0x7fffu + ((u >> 16) & 1u);
    return (unsigned short)(u >> 16);
}
__device__ __forceinline__ float bf16_to_f(unsigned short h) {
    return __uint_as_float(((unsigned)h) << 16);
}

// numpy pairwise_sum over 64 squared elements (exact np emulation)
__device__ __forceinline__ float np_pairwise_sq64(const float* v) {
    float r[8];
#pragma unroll
    for (int j = 0; j < 8; j++) r[j] = __fmul_rn(v[j], v[j]);
#pragma unroll
    for (int i = 8; i < 64; i += 8) {
#pragma unroll
        for (int j = 0; j < 8; j++)
            r[j] = __fadd_rn(r[j], __fmul_rn(v[i + j], v[i + j]));
    }
    return __fadd_rn(__fadd_rn(__fadd_rn(r[0], r[1]), __fadd_rn(r[2], r[3])),
                     __fadd_rn(__fadd_rn(r[4], r[5]), __fadd_rn(r[6], r[7])));
}

// ---------------- kernel 0: prep (wsq + wsqb + packedW + zero-init) ----------
__global__ __launch_bounds__(256) void vq_prep(const float* __restrict__ weight,
                                               float* __restrict__ wsq,
                                               float* __restrict__ wsqb,
                                               int4* __restrict__ packedW,
                                               int* __restrict__ rcount,
                                               float* __restrict__ loss_out) {
    int tid = threadIdx.x;
    if (blockIdx.x == 0 && tid == 0) { *rcount = 0; *loss_out = 0.f; }

    if (tid < 64) {
        int k = blockIdx.x * 64 + tid;
        float w[64];
        const float4* wp = (const float4*)(weight + (size_t)k * DIM);
#pragma unroll
        for (int i = 0; i < 16; i++) {
            float4 t = wp[i];
            w[4 * i] = t.x; w[4 * i + 1] = t.y; w[4 * i + 2] = t.z; w[4 * i + 3] = t.w;
        }
        float s = np_pairwise_sq64(w);
        wsq[k] = s;
        wsqb[k] = s + 8.0f;   // BIAS folded for the MFMA accumulator init
    }

    int wave = tid >> 6;
    int lane = tid & 63;
    int tile = blockIdx.x * 4 + wave;     // 0..511
    int code = tile * 16 + (lane & 15);
    int kq = (lane >> 4) * 8;
    const float* wr = weight + (size_t)code * DIM;

    union { bf16x8 v; int4 q; } hi0, hi1, lo0, lo1;
#pragma unroll
    for (int j = 0; j < 8; j++) {
        float a = -2.0f * wr[kq + j];
        unsigned short ha = bf16_rne(a);
        hi0.v[j] = (short)ha;
        lo0.v[j] = (short)bf16_rne(a - bf16_to_f(ha));
        float b = -2.0f * wr[32 + kq + j];
        unsigned short hb = bf16_rne(b);
        hi1.v[j] = (short)hb;
        lo1.v[j] = (short)bf16_rne(b - bf16_to_f(hb));
    }
    size_t base = (size_t)tile * 4 * 64;
    packedW[base + 0 * 64 + lane] = hi0.q;
    packedW[base + 1 * 64 + lane] = hi1.q;
    packedW[base + 2 * 64 + lane] = lo0.q;
    packedW[base + 3 * 64 + lane] = lo1.q;
}

// ---------------- kernel 1: MFMA argmin top-2 over a 2048-code chunk ----------
// grid (256, KSPLIT) x 256. Block: 128 rows; wave: 32 rows (2 row-tiles).
__global__ __launch_bounds__(256) void vq_argmin_mfma(const float* __restrict__ inp,
                                                      const int4* __restrict__ packedW,
                                                      const float* __restrict__ wsqb,
                                                      unsigned long long* __restrict__ bestk,
                                                      unsigned* __restrict__ secd) {
    __shared__ int4 sB[2048];   // 32 KB: two 16 KB buffers (4 code-tiles each)
    int wave = threadIdx.x >> 6;
    int lane = threadIdx.x & 63;
    int rbase = blockIdx.x * 128 + wave * 32;
    int kbase = blockIdx.y * KCHUNK;

    // A fragments from raw fp32 rows: lane holds A[m=lane&15][k=(lane>>4)*8+j]
    int kq = (lane >> 4) * 8;
    bf16x8 ah[2][2], al[2][2];   // [row-tile][k-chunk]
#pragma unroll
    for (int rt = 0; rt < 2; rt++) {
        const float* xp = inp + (size_t)(rbase + rt * 16 + (lane & 15)) * DIM;
#pragma unroll
        for (int kc = 0; kc < 2; kc++) {
            const float* xq = xp + kc * 32 + kq;
#pragma unroll
            for (int j = 0; j < 8; j++) {
                float a = xq[j];
                unsigned short h = bf16_rne(a);
                ah[rt][kc][j] = (short)h;
                al[rt][kc][j] = (short)bf16_rne(a - bf16_to_f(h));
            }
        }
    }

    unsigned best[8], sec[8];
#pragma unroll
    for (int s = 0; s < 8; s++) { best[s] = 0xFFFFFFFFu; sec[s] = 0xFFFFFFFFu; }

    // stage one 16 KB group (4 tiles, wave w stages tile w) into buffer `buf`
#define STAGE(buf, g) do {                                                        \
        const char* _src = (const char*)packedW +                                 \
            ((size_t)(kbase >> 4) + (size_t)(g) * 4 + wave) * 4096;               \
        char* _dst = (char*)sB + (buf) * 16384 + wave * 4096;                     \
        _Pragma("unroll")                                                         \
        for (int _i = 0; _i < 4; _i++)                                            \
            __builtin_amdgcn_global_load_lds(                                     \
                (const __attribute__((address_space(1))) unsigned int*)(_src + _i * 1024 + lane * 16), \
                (__attribute__((address_space(3))) unsigned int*)(_dst + _i * 1024), \
                16, 0, 0);                                                        \
    } while (0)

    STAGE(0, 0);
    __syncthreads();   // drains vmcnt(0): buf0 ready

    for (int g = 0; g < 32; g++) {
        int buf = g & 1;
        if (g + 1 < 32) STAGE(buf ^ 1, g + 1);   // issue next-group loads FIRST
        int cb = kbase + g * 64 + (lane & 15);
#pragma unroll
        for (int t = 0; t < 4; t++) {
            const int4* bp = sB + buf * 1024 + t * 256;
            union { int4 q; bf16x8 v; } bh0, bh1, bl0, bl1;
            bh0.q = bp[0 * 64 + lane];
            bh1.q = bp[1 * 64 + lane];
            bl0.q = bp[2 * 64 + lane];
            bl1.q = bp[3 * 64 + lane];
            float wq = wsqb[cb + t * 16];
            unsigned tid7 = (unsigned)(g * 4 + t);   // 0..127 tile id in chunk
#pragma unroll
            for (int rt = 0; rt < 2; rt++) {
                f32x4 acc = {wq, wq, wq, wq};   // c = wsq + 8 - 2*dot, directly
                acc = __builtin_amdgcn_mfma_f32_16x16x32_bf16(ah[rt][0], bh0.v, acc, 0, 0, 0);
                acc = __builtin_amdgcn_mfma_f32_16x16x32_bf16(ah[rt][1], bh1.v, acc, 0, 0, 0);
                acc = __builtin_amdgcn_mfma_f32_16x16x32_bf16(al[rt][0], bh0.v, acc, 0, 0, 0);
                acc = __builtin_amdgcn_mfma_f32_16x16x32_bf16(al[rt][1], bh1.v, acc, 0, 0, 0);
                acc = __builtin_amdgcn_mfma_f32_16x16x32_bf16(ah[rt][0], bl0.v, acc, 0, 0, 0);
                acc = __builtin_amdgcn_mfma_f32_16x16x32_bf16(ah[rt][1], bl1.v, acc, 0, 0, 0);
#pragma unroll
                for (int r = 0; r < 4; r++) {
                    // 4 VALU ops: v_and_or_b32, v_max_u32, v_min_u32, v_min_u32
                    unsigned key = (__float_as_uint(acc[r]) & KEYMASK) | tid7;
                    int s = rt * 4 + r;
                    unsigned mx = best[s] > key ? best[s] : key;
                    sec[s] = sec[s] < mx ? sec[s] : mx;
                    best[s] = best[s] < key ? best[s] : key;
                }
            }
        }
        __syncthreads();   // one barrier per group; also drains next-group loads
    }
#undef STAGE

    // reduce across the 16 code-columns (lanes sharing lane>>4 group)
    unsigned col[8];
#pragma unroll
    for (int s = 0; s < 8; s++) col[s] = lane & 15;
#pragma unroll
    for (int m = 1; m < 16; m <<= 1) {
#pragma unroll
        for (int s = 0; s < 8; s++) {
            unsigned ok = (unsigned)__shfl_xor((int)best[s], m, 64);
            unsigned os = (unsigned)__shfl_xor((int)sec[s], m, 64);
            unsigned oc = (unsigned)__shfl_xor((int)col[s], m, 64);
            unsigned mx = best[s] > ok ? best[s] : ok;
            unsigned mn2 = sec[s] < os ? sec[s] : os;
            sec[s] = mn2 < mx ? mn2 : mx;
            bool take = ok < best[s];
            best[s] = take ? ok : best[s];
            col[s] = take ? oc : col[s];
        }
    }
    if ((lane & 15) == 0) {
        int g4 = lane >> 4;
#pragma unroll
        for (int rt = 0; rt < 2; rt++)
#pragma unroll
            for (int r = 0; r < 4; r++) {
                int row = rbase + rt * 16 + g4 * 4 + r;
                int s = rt * 4 + r;
                int code = kbase + (int)(best[s] & 127u) * 16 + (int)col[s];
                bestk[(size_t)blockIdx.y * N_ROWS + row] =
                    ((unsigned long long)best[s] << 32) | (unsigned)code;
                secd[(size_t)blockIdx.y * N_ROWS + row] = sec[s];
            }
    }
}

// ---------------- kernel 2: merge chunks, flag near-ties ----------------
__global__ __launch_bounds__(256) void vq_merge(const unsigned long long* __restrict__ bestk,
                                                const unsigned* __restrict__ secd,
                                                int* __restrict__ final_idx,
                                                int* __restrict__ recheck_rows,
                                                int* __restrict__ recheck_count,
                                                unsigned long long* __restrict__ rrk) {
    int row = blockIdx.x * 256 + threadIdx.x;

    unsigned long long ks[KSPLIT];
    unsigned ss[KSPLIT];
#pragma unroll
    for (int c = 0; c < KSPLIT; c++) {
        ks[c] = bestk[(size_t)c * N_ROWS + row];
        ss[c] = secd[(size_t)c * N_ROWS + row];
    }

    unsigned long long k1 = ks[0];
#pragma unroll
    for (int c = 1; c < KSPLIT; c++) k1 = (ks[c] < k1) ? ks[c] : k1;

    unsigned d2 = 0xFFFFFFFFu;
#pragma unroll
    for (int c = 0; c < KSPLIT; c++) {
        if (ks[c] != k1) {
            unsigned b = (unsigned)(ks[c] >> 32);
            d2 = b < d2 ? b : d2;
        }
        d2 = ss[c] < d2 ? ss[c] : d2;
    }

    final_idx[row] = (int)(k1 & 0xffffffffull);
    float f1 = __uint_as_float(((unsigned)(k1 >> 32)) & KEYMASK);
    float f2 = __uint_as_float(d2 & KEYMASK);
    if (f2 - f1 < MARGIN) {
        int slot = atomicAdd(recheck_count, 1);
        recheck_rows[slot] = row;
        rrk[slot] = 0xFFFFFFFFFFFFFFFFull;   // init combine key for this slot
    }
}

// ---------------- kernel 3: np-exact rescan of flagged rows (parallel) -------
// grid (256 row-slots, 8 code-slices) x 256. Each block: one (row, 1024-code
// slice). Thread t scans codes slice*1024 + t + 256*c, c=0..3 (ascending ->
// np first-min tie-break within thread; strict-less keeps smallest index).
// Cross-thread: LDS tree with (dist, idx) tie-break. Cross-slice: atomicMin
// on u64 ordered key.
__global__ __launch_bounds__(256) void vq_recheck_np(const float* __restrict__ inp,
                                                     const float* __restrict__ weight,
                                                     const float* __restrict__ wsq,
                                                     const int* __restrict__ recheck_rows,
                                                     const int* __restrict__ recheck_count,
                                                     unsigned long long* __restrict__ rrk) {
    __shared__ float xs[DIM];
    __shared__ float x2s;
    __shared__ float rd[256];
    __shared__ int   ri[256];
    int tid = threadIdx.x;
    int slice = blockIdx.y;
    int cnt = *recheck_count;
    if (cnt > N_ROWS) cnt = N_ROWS;

    for (int li = blockIdx.x; li < cnt; li += gridDim.x) {
        int row = recheck_rows[li];
        if (tid < DIM) xs[tid] = inp[(size_t)row * DIM + tid];
        __syncthreads();
        if (tid == 0) x2s = np_pairwise_sq64(xs);
        __syncthreads();
        float x2 = x2s;

        float bd = 3.402823466e+38f;
        int bi = 0x7fffffff;
#pragma unroll
        for (int c = 0; c < 4; c++) {
            int code = slice * 1024 + c * 256 + tid;
            const float* wp = weight + (size_t)code * DIM;
            float s = 0.f;
#pragma unroll
            for (int i = 0; i < DIM; i++) s = __builtin_fmaf(xs[i], wp[i], s);
            float t1 = __fadd_rn(x2, wsq[code]);
            float d  = __fsub_rn(t1, __fmul_rn(2.0f, s));
            if (d < bd) { bd = d; bi = code; }
        }
        rd[tid] = bd; ri[tid] = bi;
        __syncthreads();
        for (int s = 128; s > 0; s >>= 1) {
            if (tid < s) {
                if (rd[tid + s] < rd[tid] ||
                    (rd[tid + s] == rd[tid] && ri[tid + s] < ri[tid])) {
                    rd[tid] = rd[tid + s]; ri[tid] = ri[tid + s];
                }
            }
            __syncthreads();
        }
        if (tid == 0) {
            unsigned long long key =
                ((unsigned long long)f2u_ord(rd[0]) << 32) | (unsigned)ri[0];
            atomicMin(rrk + li, key);
        }
        __syncthreads();
    }
}

// ---------------- kernel 3b: scatter recheck winners into final_idx ----------
__global__ __launch_bounds__(256) void vq_scatter(const int* __restrict__ recheck_rows,
                                                  const int* __restrict__ recheck_count,
                                                  const unsigned long long* __restrict__ rrk,
                                                  int* __restrict__ final_idx) {
    int cnt = *recheck_count;
    if (cnt > N_ROWS) cnt = N_ROWS;
    for (int li = blockIdx.x * 256 + threadIdx.x; li < cnt; li += gridDim.x * 256)
        final_idx[recheck_rows[li]] = (int)(rrk[li] & 0xffffffffull);
}

// ---------------- kernel 4: gather + STE + loss + index write ----------------
__global__ __launch_bounds__(256) void vq_final(const float* __restrict__ inp,
                                                const float* __restrict__ weight,
                                                const int* __restrict__ final_idx,
                                                float* __restrict__ out) {
    int gid = blockIdx.x * 256 + threadIdx.x;
    int row = gid >> 4;
    int sub = gid & 15;

    int idx = final_idx[row];

    float4 x = ((const float4*)inp)[gid];
    float4 w = ((const float4*)weight)[idx * 16 + sub];

    float4 q;
    q.x = x.x + (w.x - x.x);
    q.y = x.y + (w.y - x.y);
    q.z = x.z + (w.z - x.z);
    q.w = x.w + (w.w - x.w);
    ((float4*)(out + OUT_Q))[gid] = q;

    if (sub == 0) out[OUT_IDX + row] = (float)idx;

    float dx = w.x - x.x, dy = w.y - x.y, dz = w.z - x.z, dw = w.w - x.w;
    float lp = dx * dx + dy * dy + dz * dz + dw * dw;

#pragma unroll
    for (int o = 32; o > 0; o >>= 1) lp += __shfl_down(lp, o, 64);

    __shared__ float red[4];
    int wid = threadIdx.x >> 6;
    int lane = threadIdx.x & 63;
    if (lane == 0) red[wid] = lp;
    __syncthreads();
    if (threadIdx.x == 0) {
        float bs = red[0] + red[1] + red[2] + red[3];
        atomicAdd(out + OUT_LOSS, bs * (0.25f / 2097152.f));
    }
}

extern "C" void kernel_launch(void* const* d_in, const int* in_sizes, int n_in,
                              void* d_out, int out_size, void* d_ws, size_t ws_size,
                              hipStream_t stream) {
    const float* inp = (const float*)d_in[0];
    const float* weight = (const float*)d_in[1];
    float* out = (float*)d_out;

    char* ws = (char*)d_ws;
    unsigned long long* bestk = (unsigned long long*)ws;               // 1 MB
    unsigned* secd  = (unsigned*)(ws + (size_t)KSPLIT * N_ROWS * 8);   // 512 KB
    char* p         = ws + (size_t)KSPLIT * N_ROWS * 12;
    int* final_idx  = (int*)p;                                         // 128 KB
    int* rrows      = (int*)(p + (size_t)N_ROWS * 4);                  // 128 KB
    int* rcount     = (int*)(p + (size_t)N_ROWS * 8);                  // 256 B
    float* wsq      = (float*)(p + (size_t)N_ROWS * 8 + 256);          // 32 KB
    float* wsqb     = (float*)(p + (size_t)N_ROWS * 8 + 256 + 32768);  // 32 KB
    int4* packedW   = (int4*)(p + (size_t)N_ROWS * 8 + 256 + 65536);   // 2 MB
    unsigned long long* rrk =
        (unsigned long long*)(p + (size_t)N_ROWS * 8 + 256 + 65536 + 2097152); // 256 KB

    vq_prep<<<128, 256, 0, stream>>>(weight, wsq, wsqb, packedW, rcount, out + OUT_LOSS);
    vq_argmin_mfma<<<dim3(N_ROWS / 128, KSPLIT), 256, 0, stream>>>(inp, packedW, wsqb, bestk, secd);
    vq_merge<<<N_ROWS / 256, 256, 0, stream>>>(bestk, secd, final_idx, rrows, rcount, rrk);
    vq_recheck_np<<<dim3(256, 8), 256, 0, stream>>>(inp, weight, wsq, rrows, rcount, rrk);
    vq_scatter<<<32, 256, 0, stream>>>(rrows, rcount, rrk, final_idx);
    vq_final<<<(N_ROWS * DIM / 4) / 256, 256, 0, stream>>>(inp, weight, final_idx, out);
}